// Round 4
// baseline (85.185 us; speedup 1.0000x reference)
//
#include <hip/hip_runtime.h>
#include <math.h>

// ChamferLikeDistanceLoss on MI355X (gfx950)
// B=4, 1x64x64 fp32. out = mean_i min_j |g_i - b_j| + mean_j min_i |g_i - b_j|
// g = sobel-magnitude(depth_pred), b = boundary_gt, per batch.
//
// R4: ONE kernel node, zero memsets.
//  - Scalar-value chamfer == 1-D nearest-value scan. Ring-of-queries over
//    refs-in-VGPRs (R3, absmax 0.0) kept as the scan engine.
//  - dir0 blocks: queries = sobel of own 64 pixels (row-uniform loads +
//    shfl neighbors); refs = bnd (16x dwordx4).
//  - dir1 blocks: stage depth image (16 KB) to LDS, compute all 4096 sobel
//    refs in-register (clamped indices + cndmask zeros, no divergent loads).
//  - Reduction: R3's 512 same-address fp atomicAdds serialize at the
//    coherence point (suspected multi-us tail). Now: partial -> ws[bx]
//    (agent-scope store), counter fetch_add; LAST block sums 512 partials
//    and writes out directly. Counter starts at the documented 0xAA poison
//    (0xAAAAAAAA), so no memset node is needed; ==511 fallback covers a
//    zero-initialized counter.

#define N_PIX 4096
#define POISON_U 0xAAAAAAAAu

__global__ __launch_bounds__(64) void chamfer_fused_kernel(
    const float* __restrict__ depth, const float* __restrict__ bnd,
    float* __restrict__ out, float* __restrict__ ws,
    int blocks_per_dir, int n_blocks, float inv_count)
{
    __shared__ float lds[N_PIX];           // dir1: depth image staging (16 KB)

    const int lane = threadIdx.x;
    const int bx   = blockIdx.x;
    const int dir  = (bx >= blocks_per_dir) ? 1 : 0;
    const int rem  = dir ? (bx - blocks_per_dir) : bx;
    const int batch = rem >> 6;            // 64 query-waves per batch
    const int qblk  = rem & 63;

    const float* __restrict__ db = depth + batch * N_PIX;
    const float* __restrict__ bb = bnd   + batch * N_PIX;

    float q;
    float r[64];

    if (dir == 0) {
        // ---- queries: g at row y=qblk (uniform), col x=lane ----
        const int y = qblk;
        const float c = db[y * 64 + lane];
        const float t = (y > 0)  ? db[(y - 1) * 64 + lane] : 0.f;  // uniform branch
        const float b = (y < 63) ? db[(y + 1) * 64 + lane] : 0.f;
        // neighbors via shfl (all lanes execute), zero at x edges
        const int lm = (lane - 1) & 63, lp = (lane + 1) & 63;
        const float tl = (lane > 0)  ? __shfl(t, lm) : 0.f;
        const float cl = (lane > 0)  ? __shfl(c, lm) : 0.f;
        const float bl = (lane > 0)  ? __shfl(b, lm) : 0.f;
        const float tr = (lane < 63) ? __shfl(t, lp) : 0.f;
        const float cr = (lane < 63) ? __shfl(c, lp) : 0.f;
        const float br = (lane < 63) ? __shfl(b, lp) : 0.f;
        const float gx = (tl - tr) + 2.f * (cl - cr) + (bl - br);
        const float gy = (tl + 2.f * t + tr) - (bl + 2.f * b + br);
        q = sqrtf(gx * gx + gy * gy + 1e-8f);
        // ---- refs: boundary values, 64/lane ----
        const float4* __restrict__ r4 = (const float4*)bb;
        #pragma unroll
        for (int j = 0; j < 16; ++j) {
            const float4 v = r4[j * 64 + lane];
            r[4 * j + 0] = v.x; r[4 * j + 1] = v.y;
            r[4 * j + 2] = v.z; r[4 * j + 3] = v.w;
        }
    } else {
        // ---- stage depth image into LDS (coalesced) ----
        const float4* __restrict__ d4 = (const float4*)db;
        float4* l4 = (float4*)lds;
        #pragma unroll
        for (int j = 0; j < 16; ++j) l4[j * 64 + lane] = d4[j * 64 + lane];
        __syncthreads();
        // ---- queries: boundary values ----
        q = bb[qblk * 64 + lane];
        // ---- refs: sobel for pixels p = j*256 + 4*lane + c ----
        const int y_off = lane >> 4;          // 0..3
        const int x0    = (lane & 15) * 4;    // 0,4,...,60
        const bool has_l = (x0 > 0), has_r = (x0 < 60);
        const int xm = (x0 - 1) & 63, xp = (x0 + 4) & 63;
        #pragma unroll
        for (int j = 0; j < 16; ++j) {
            const int y = j * 4 + y_off;
            const bool has_t = (y > 0), has_b = (y < 63);
            const int ym = has_t ? y - 1 : 0;
            const int yp = has_b ? y + 1 : 63;
            const float4 C4 = l4[y * 16 + (x0 >> 2)];
            const float4 T4 = l4[ym * 16 + (x0 >> 2)];
            const float4 B4 = l4[yp * 16 + (x0 >> 2)];
            float trow[6], crow[6], brow[6];
            crow[0] = has_l ? lds[y * 64 + xm] : 0.f;
            crow[5] = has_r ? lds[y * 64 + xp] : 0.f;
            crow[1] = C4.x; crow[2] = C4.y; crow[3] = C4.z; crow[4] = C4.w;
            trow[0] = (has_l && has_t) ? lds[ym * 64 + xm] : 0.f;
            trow[5] = (has_r && has_t) ? lds[ym * 64 + xp] : 0.f;
            trow[1] = has_t ? T4.x : 0.f; trow[2] = has_t ? T4.y : 0.f;
            trow[3] = has_t ? T4.z : 0.f; trow[4] = has_t ? T4.w : 0.f;
            brow[0] = (has_l && has_b) ? lds[yp * 64 + xm] : 0.f;
            brow[5] = (has_r && has_b) ? lds[yp * 64 + xp] : 0.f;
            brow[1] = has_b ? B4.x : 0.f; brow[2] = has_b ? B4.y : 0.f;
            brow[3] = has_b ? B4.z : 0.f; brow[4] = has_b ? B4.w : 0.f;
            #pragma unroll
            for (int cc = 0; cc < 4; ++cc) {
                const float gx = (trow[cc] - trow[cc + 2])
                               + 2.f * (crow[cc] - crow[cc + 2])
                               + (brow[cc] - brow[cc + 2]);
                const float gy = (trow[cc] + 2.f * trow[cc + 1] + trow[cc + 2])
                               - (brow[cc] + 2.f * brow[cc + 1] + brow[cc + 2]);
                r[4 * j + cc] = sqrtf(gx * gx + gy * gy + 1e-8f);
            }
        }
    }

    // ---- ring scan: (q, m) rotate; each step scans this lane's 64 refs ----
    float m = 1e30f;
    const int src = (lane + 1) & 63;
    for (int step = 0; step < 64; ++step) {
        const float q_next = __shfl(q, src);
        float t0 = 1e30f, t1 = 1e30f;
        #pragma unroll
        for (int k = 0; k < 64; k += 4) {
            t0 = fminf(fminf(t0, fabsf(q - r[k + 0])), fabsf(q - r[k + 1]));
            t1 = fminf(fminf(t1, fabsf(q - r[k + 2])), fabsf(q - r[k + 3]));
        }
        m = fminf(m, fminf(t0, t1));
        m = __shfl(m, src);
        q = q_next;
    }

    // ---- wave sum ----
    #pragma unroll
    for (int o = 32; o > 0; o >>= 1) m += __shfl_down(m, o);

    // ---- partial -> ws[bx]; last block reduces and writes out ----
    unsigned* cnt = (unsigned*)(ws + n_blocks);
    int last = 0;
    if (lane == 0) {
        __hip_atomic_store(&ws[bx], m, __ATOMIC_RELEASE, __HIP_MEMORY_SCOPE_AGENT);
        const unsigned old = __hip_atomic_fetch_add(cnt, 1u, __ATOMIC_ACQ_REL,
                                                    __HIP_MEMORY_SCOPE_AGENT);
        last = (old == POISON_U + (unsigned)(n_blocks - 1)) ||
               (old == (unsigned)(n_blocks - 1));
    }
    last = __shfl(last, 0);
    if (last) {
        float s = 0.f;
        for (int i = lane; i < n_blocks; i += 64)
            s += __hip_atomic_load(&ws[i], __ATOMIC_RELAXED, __HIP_MEMORY_SCOPE_AGENT);
        #pragma unroll
        for (int o = 32; o > 0; o >>= 1) s += __shfl_down(s, o);
        if (lane == 0) out[0] = s * inv_count;
    }
}

extern "C" void kernel_launch(void* const* d_in, const int* in_sizes, int n_in,
                              void* d_out, int out_size, void* d_ws, size_t ws_size,
                              hipStream_t stream) {
    const float* depth = (const float*)d_in[0];
    const float* bnd   = (const float*)d_in[1];
    float* out = (float*)d_out;
    float* ws  = (float*)d_ws;

    const int B = in_sizes[0] / N_PIX;      // 4
    const int blocks_per_dir = B * 64;      // 256
    const int n_blocks = 2 * blocks_per_dir;// 512
    const float inv_count = 1.0f / (float)(B * N_PIX);

    hipLaunchKernelGGL(chamfer_fused_kernel, dim3(n_blocks), dim3(64), 0, stream,
                       depth, bnd, out, ws, blocks_per_dir, n_blocks, inv_count);
}

// Round 5
// 73.138 us; speedup vs baseline: 1.1647x; 1.1647x over previous
//
#include <hip/hip_runtime.h>
#include <math.h>

// ChamferLikeDistanceLoss on MI355X (gfx950)
// B=4, 1x64x64 fp32. out = mean_i min_j |g_i - b_j| + mean_j min_i |g_i - b_j|
// g = sobel-magnitude(depth_pred), b = boundary_gt, per batch.
//
// R5: ring engine (R3, absmax 0.0) + full SIMD coverage + safe reduction.
//  - 512 blocks x 256 thr: block = (dir, batch, query-row qblk). Each of the
//    4 waves holds a QUARTER of the 4096 refs in VGPRs (16/lane); the 64
//    queries rotate around each wave (shfl ring). 2048 waves = 2/SIMD
//    (R3/R4 had 512 waves = 0.5/SIMD -- half the SIMDs idle).
//  - Cross-wave per-query min via 1 KB LDS, wave 0 sums.
//  - R4's counter+last-block reduction hit cross-XCD staleness (absmax
//    0.0156, ~2-3 lost partials). Back to same-address atomics (device
//    scope, R1/R3-proven): CAS-or-add epilogue handles the 0xAA-poisoned
//    d_out with no memset node: first block CASes poison->val, rest add.
//    Works for zeroed d_out too (all CAS fail -> all add).
//  - Sobel: rolling 3-row registers + shfl_up/down(.,1) (DPP) -- no LDS
//    staging, no divergent-address selects.

#define N_PIX 4096

// Sobel magnitude at (row of t/c/b registers, x=lane). t/c/b are rows y-1,y,y+1
// at x=lane (0 outside the image). Zero-padded 3x3, XLA cross-correlation.
__device__ __forceinline__ float sobel3(float t, float c, float b, int lane) {
    const float tl = (lane > 0)  ? __shfl_up(t, 1)   : 0.f;
    const float cl = (lane > 0)  ? __shfl_up(c, 1)   : 0.f;
    const float bl = (lane > 0)  ? __shfl_up(b, 1)   : 0.f;
    const float tr = (lane < 63) ? __shfl_down(t, 1) : 0.f;
    const float cr = (lane < 63) ? __shfl_down(c, 1) : 0.f;
    const float br = (lane < 63) ? __shfl_down(b, 1) : 0.f;
    const float gx = (tl - tr) + 2.f * (cl - cr) + (bl - br);
    const float gy = (tl + 2.f * t + tr) - (bl + 2.f * b + br);
    return sqrtf(gx * gx + gy * gy + 1e-8f);
}

__global__ __launch_bounds__(256) void chamfer_fused_kernel(
    const float* __restrict__ depth, const float* __restrict__ bnd,
    float* __restrict__ out, int blocks_per_dir, float inv_count)
{
    __shared__ float qmin[4][64];   // per-wave, per-query partial mins (1 KB)

    const int tid  = threadIdx.x;
    const int lane = tid & 63;
    const int w    = tid >> 6;                  // wave 0..3 = ref quarter
    const int bx   = blockIdx.x;
    const int dir  = (bx >= blocks_per_dir) ? 1 : 0;
    const int rem  = dir ? (bx - blocks_per_dir) : bx;
    const int batch = rem >> 6;                 // 64 query-rows per batch
    const int qblk  = rem & 63;                 // query row

    const float* __restrict__ db = depth + batch * N_PIX;
    const float* __restrict__ bb = bnd   + batch * N_PIX;

    float q;        // this lane's query value
    float r[16];    // this wave's ref subset, 16/lane (wave covers 1024 refs)

    if (dir == 0) {
        // queries: g at row qblk, x=lane (uniform row -> 3 coalesced loads)
        const float c = db[qblk * 64 + lane];
        const float t = (qblk > 0)  ? db[(qblk - 1) * 64 + lane] : 0.f;
        const float b = (qblk < 63) ? db[(qblk + 1) * 64 + lane] : 0.f;
        q = sobel3(t, c, b, lane);
        // refs: boundary values, quarter w: floats [w*1024, w*1024+1024)
        const float4* __restrict__ r4 = (const float4*)bb;
        #pragma unroll
        for (int k = 0; k < 4; ++k) {
            const float4 v = r4[w * 256 + k * 64 + lane];
            r[4 * k + 0] = v.x; r[4 * k + 1] = v.y;
            r[4 * k + 2] = v.z; r[4 * k + 3] = v.w;
        }
    } else {
        // queries: boundary values at row qblk
        q = bb[qblk * 64 + lane];
        // refs: g at rows [w*16, w*16+16), x=lane. Rolling 3-row registers.
        const int y0 = w * 16;
        float c = db[y0 * 64 + lane];
        float t = (y0 > 0) ? db[(y0 - 1) * 64 + lane] : 0.f;
        #pragma unroll
        for (int k = 0; k < 16; ++k) {
            const int y = y0 + k;
            const float b = (y < 63) ? db[(y + 1) * 64 + lane] : 0.f;
            r[k] = sobel3(t, c, b, lane);
            t = c; c = b;
        }
    }

    // Ring: (q, m) rotate around the wave; each step scans 16 refs with two
    // independent min3 chains. Both shfls have ~a full step of slack.
    float m = 1e30f;
    const int src = (lane + 1) & 63;
    for (int step = 0; step < 64; ++step) {
        const float q_next = __shfl(q, src);
        float t0 = 1e30f, t1 = 1e30f;
        #pragma unroll
        for (int k = 0; k < 16; k += 4) {
            t0 = fminf(fminf(t0, fabsf(q - r[k + 0])), fabsf(q - r[k + 1]));
            t1 = fminf(fminf(t1, fabsf(q - r[k + 2])), fabsf(q - r[k + 3]));
        }
        m = fminf(m, fminf(t0, t1));
        m = __shfl(m, src);
        q = q_next;
    }
    // Home: lane L holds min over wave-w's 1024 refs for query (qblk, L).

    qmin[w][lane] = m;
    __syncthreads();

    if (w == 0) {
        // per-query min across the 4 ref-quarters, then sum the 64 queries
        float mq = fminf(fminf(qmin[0][lane], qmin[1][lane]),
                         fminf(qmin[2][lane], qmin[3][lane]));
        #pragma unroll
        for (int o = 32; o > 0; o >>= 1) mq += __shfl_down(mq, o);
        if (lane == 0) {
            const float val = mq * inv_count;
            // CAS-or-add: first block converts the 0xAA poison to its value,
            // everyone else accumulates. Also correct if out starts at 0.
            const unsigned old = atomicCAS((unsigned*)out, 0xAAAAAAAAu,
                                           __float_as_uint(val));
            if (old != 0xAAAAAAAAu) atomicAdd(out, val);
        }
    }
}

extern "C" void kernel_launch(void* const* d_in, const int* in_sizes, int n_in,
                              void* d_out, int out_size, void* d_ws, size_t ws_size,
                              hipStream_t stream) {
    const float* depth = (const float*)d_in[0];
    const float* bnd   = (const float*)d_in[1];
    float* out = (float*)d_out;

    const int B = in_sizes[0] / N_PIX;          // 4
    const int blocks_per_dir = B * 64;          // 256
    const float inv_count = 1.0f / (float)(B * N_PIX);

    hipLaunchKernelGGL(chamfer_fused_kernel, dim3(2 * blocks_per_dir), dim3(256),
                       0, stream, depth, bnd, out, blocks_per_dir, inv_count);
}